// Round 1
// baseline (2407.145 us; speedup 1.0000x reference)
//
#include <hip/hip_runtime.h>

#define S_LEN 2048
#define B_SZ  64
#define D_IN  128
#define H_SZ  128
#define G4    512   // 4*H

typedef __attribute__((ext_vector_type(4))) float     floatx4;
typedef __attribute__((ext_vector_type(2))) float     floatx2;
typedef __attribute__((ext_vector_type(8))) _Float16  half8;
typedef __attribute__((ext_vector_type(2))) _Float16  half2_t;

// DPP quad_perm helper (VALU pipe). CTRL: xor1=0xB1, xor2=0x4E.
template<int CTRL>
__device__ __forceinline__ float qperm(float v) {
  return __int_as_float(
      __builtin_amdgcn_mov_dpp(__float_as_int(v), CTRL, 0xF, 0xF, true));
}

// half2 extraction from half8 — register aliasing, no union round-trip
template<int P>
__device__ __forceinline__ half2_t h2ext(half8 v) {
  return __builtin_shufflevector(v, v, 2 * P, 2 * P + 1);
}

// Workgroup barrier that drains ONLY lgkmcnt (LDS), leaving global loads/
// stores (vmcnt) in flight. __syncthreads() would drain vmcnt(0) each step.
__device__ __forceinline__ void lds_barrier() {
  asm volatile("s_waitcnt lgkmcnt(0)\n\ts_barrier" ::: "memory");
}

// ---------------------------------------------------------------------------
// Kernel 1: gates_x[sb][n] = (sum_k X[sb][k]*W_ih[n][k] + b[n]) * sc(type),
// stored f16.  sc = -log2e for i,f,o; -2log2e for g (folds the sigmoid/tanh
// exp2 scaling into the data so lstm_rev's activation chain is shorter).
// 256 rows/WG: W chunk staged ONCE per 4 row-groups.
// ---------------------------------------------------------------------------
__global__ __launch_bounds__(256) void gx_gemm(
    const float* __restrict__ X,       // [S*B][128]
    const float* __restrict__ Wih,     // [512][128]
    const float* __restrict__ bias,    // [512]
    _Float16* __restrict__ gx)         // [S*B][512] f16, pre-scaled
{
  __shared__ _Float16 Wl[128][136];
  const int tid  = threadIdx.x;
  const int lane = tid & 63;
  const int wv   = tid >> 6;
  const int R0   = blockIdx.x * 256;
  const int m    = lane & 15;
  const int q    = lane >> 4;

  const float LOG2E = 1.4426950408889634f;

  // A-fragments for 4 row-groups of 64 rows each
  half8 afrag[4][4];
  #pragma unroll
  for (int rg = 0; rg < 4; ++rg) {
    const float* xrow = X + (size_t)(R0 + rg * 64 + wv * 16 + m) * D_IN;
    #pragma unroll
    for (int kf = 0; kf < 4; ++kf) {
      const int k0 = kf * 32 + q * 8;
      floatx4 v0 = *(const floatx4*)(xrow + k0);
      floatx4 v1 = *(const floatx4*)(xrow + k0 + 4);
      half8 a;
      a[0] = (_Float16)v0.x; a[1] = (_Float16)v0.y;
      a[2] = (_Float16)v0.z; a[3] = (_Float16)v0.w;
      a[4] = (_Float16)v1.x; a[5] = (_Float16)v1.y;
      a[6] = (_Float16)v1.z; a[7] = (_Float16)v1.w;
      afrag[rg][kf] = a;
    }
  }

  for (int nc = 0; nc < 4; ++nc) {      // gate-type chunk (128 gate rows)
    const float sc = (nc == 2) ? (-2.0f * LOG2E) : (-LOG2E);
    __syncthreads();
    for (int i = tid; i < 128 * 32; i += 256) {
      const int row = i >> 5;
      const int c4  = (i & 31) * 4;
      floatx4 v = *(const floatx4*)(Wih + ((size_t)nc * 128 + row) * D_IN + c4);
      Wl[row][c4 + 0] = (_Float16)v.x;
      Wl[row][c4 + 1] = (_Float16)v.y;
      Wl[row][c4 + 2] = (_Float16)v.z;
      Wl[row][c4 + 3] = (_Float16)v.w;
    }
    __syncthreads();

    #pragma unroll
    for (int nt = 0; nt < 8; ++nt) {
      const int n0  = nc * 128 + nt * 16;
      const int nlo = nt * 16 + m;
      const float bv = bias[n0 + m];
      half8 bfrag[4];
      #pragma unroll
      for (int kf = 0; kf < 4; ++kf)
        bfrag[kf] = *(const half8*)(&Wl[nlo][kf * 32 + q * 8]);
      #pragma unroll
      for (int rg = 0; rg < 4; ++rg) {
        floatx4 acc = {bv, bv, bv, bv};
        #pragma unroll
        for (int kf = 0; kf < 4; ++kf)
          acc = __builtin_amdgcn_mfma_f32_16x16x32_f16(afrag[rg][kf],
                                                       bfrag[kf], acc, 0, 0, 0);
        // C layout: col = lane&15, row = q*4 + reg
        _Float16* gp =
            gx + (size_t)(R0 + rg * 64 + wv * 16 + q * 4) * G4 + n0 + m;
        #pragma unroll
        for (int r = 0; r < 4; ++r)
          gp[(size_t)r * G4] = (_Float16)(acc[r] * sc);
      }
    }
  }
}

// ---------------------------------------------------------------------------
// Kernel 2: reverse-time recurrence. NOW: one WG per TWO batches (32 WGs x
// 512 threads). Each thread runs the identical gate pipeline for both
// batches per step -> 2x independent instruction chains fill the latency
// gaps (LDS round-trip, activation chain) that dominated at 2 waves/SIMD.
// Weights (64 VGPRs) are SHARED between the two batches. One barrier now
// covers two batch-steps. gx/time prefetch deepened to distance-2 substeps
// (> HBM miss latency ~900cy).
// types: 0=i 1=f 2=g 3=o
// ---------------------------------------------------------------------------
#define DOT8(I, HV)                                                           \
  {                                                                           \
    q0a = __builtin_amdgcn_fdot2(h2ext<0>(HV), h2ext<0>(w[0][I]), q0a, false);\
    q1a = __builtin_amdgcn_fdot2(h2ext<0>(HV), h2ext<0>(w[1][I]), q1a, false);\
    q2a = __builtin_amdgcn_fdot2(h2ext<0>(HV), h2ext<0>(w[2][I]), q2a, false);\
    q3a = __builtin_amdgcn_fdot2(h2ext<0>(HV), h2ext<0>(w[3][I]), q3a, false);\
    q0a = __builtin_amdgcn_fdot2(h2ext<1>(HV), h2ext<1>(w[0][I]), q0a, false);\
    q1a = __builtin_amdgcn_fdot2(h2ext<1>(HV), h2ext<1>(w[1][I]), q1a, false);\
    q2a = __builtin_amdgcn_fdot2(h2ext<1>(HV), h2ext<1>(w[2][I]), q2a, false);\
    q3a = __builtin_amdgcn_fdot2(h2ext<1>(HV), h2ext<1>(w[3][I]), q3a, false);\
    q0b = __builtin_amdgcn_fdot2(h2ext<2>(HV), h2ext<2>(w[0][I]), q0b, false);\
    q1b = __builtin_amdgcn_fdot2(h2ext<2>(HV), h2ext<2>(w[1][I]), q1b, false);\
    q2b = __builtin_amdgcn_fdot2(h2ext<2>(HV), h2ext<2>(w[2][I]), q2b, false);\
    q3b = __builtin_amdgcn_fdot2(h2ext<2>(HV), h2ext<2>(w[3][I]), q3b, false);\
    q0b = __builtin_amdgcn_fdot2(h2ext<3>(HV), h2ext<3>(w[0][I]), q0b, false);\
    q1b = __builtin_amdgcn_fdot2(h2ext<3>(HV), h2ext<3>(w[1][I]), q1b, false);\
    q2b = __builtin_amdgcn_fdot2(h2ext<3>(HV), h2ext<3>(w[2][I]), q2b, false);\
    q3b = __builtin_amdgcn_fdot2(h2ext<3>(HV), h2ext<3>(w[3][I]), q3b, false);\
  }

// One batch's full gate pipeline for one time step. No barriers, no LDS
// writes inside (kept outside so both batches' bodies form one schedulable
// region). Returns h (meaningful on tt==3 lanes); updates c in-place.
__device__ __forceinline__ float lstm_gate(
    const _Float16* __restrict__ hr,     // LDS read buffer (prev h)
    const half8 (&w)[4][4],              // pre-scaled weights (shared)
    float gxc, float tmv, float& c,
    float wt, float bt, float am, float aa, bool odd, int tt)
{
  const float LOG2E = 1.4426950408889634f;
  half8 hv0 = *(const half8*)(hr + 0 * 32 + tt * 8);
  half8 hv1 = *(const half8*)(hr + 1 * 32 + tt * 8);
  half8 hv2 = *(const half8*)(hr + 2 * 32 + tt * 8);
  half8 hv3 = *(const half8*)(hr + 3 * 32 + tt * 8);
  float q0a = 0.f, q0b = 0.f, q1a = 0.f, q1b = 0.f;
  float q2a = 0.f, q2b = 0.f, q3a = 0.f, q3b = 0.f;
  DOT8(0, hv0); DOT8(1, hv1); DOT8(2, hv2); DOT8(3, hv3);
  float a0 = q0a + q0b, a1 = q1a + q1b, a2 = q2a + q2b, a3 = q3a + q3b;
  a0 += qperm<0xB1>(a0); a1 += qperm<0xB1>(a1);
  a2 += qperm<0xB1>(a2); a3 += qperm<0xB1>(a3);
  a0 += qperm<0x4E>(a0); a1 += qperm<0x4E>(a1);
  a2 += qperm<0x4E>(a2); a3 += qperm<0x4E>(a3);
  float pre = (tt & 1) ? ((tt & 2) ? a3 : a1) : ((tt & 2) ? a2 : a0);
  pre += gxc;  // pre is already scaled by -log2e (or -2log2e for g)
  const float e = __builtin_amdgcn_exp2f(pre);
  const float v = fmaf(am, __builtin_amdgcn_rcpf(1.0f + e), aa);
  float z = fmaf(tmv, wt, bt);             // = -log2e*(t*w_t+b_t)
  z = fminf(z, 0.0f);                      // -log2e*relu(.)
  const float d = __builtin_amdgcn_exp2f(z);
  const float p2 = qperm<0x4E>(v);
  const float fv = (tt == 1) ? v : p2;
  const float r  = odd ? fv * (d * c) : v * p2;
  const float cn = r + qperm<0xB1>(r);
  c = cn;
  const float e2 = __builtin_amdgcn_exp2f(-2.0f * LOG2E * cn);
  const float th = fmaf(2.0f, __builtin_amdgcn_rcpf(1.0f + e2), -1.0f);
  return v * th;
}

__global__ __launch_bounds__(512, 2) void lstm_rev(
    const _Float16* __restrict__ gx,        // [S*B][512] f16, pre-scaled
    const float* __restrict__ timep,        // [S*B]
    const float* __restrict__ Whh,          // [512][128]
    const float* __restrict__ w_tp,         // [128]
    const float* __restrict__ b_tp,         // [128]
    float* __restrict__ out)                // S*B*H outputs, then h, then c
{
  __shared__ __align__(16) _Float16 hbuf[2][2][H_SZ];  // [batch][pingpong][col]
  const int tid = threadIdx.x;
  const int b0  = blockIdx.x * 2;            // this WG's two batches
  const int tt  = tid & 3;
  const int col = tid >> 2;
  const int j   = tt * 128 + col;

  const float LOG2E = 1.4426950408889634f;

  // Pre-scaled f16 weights: w[ty][i] = sc(ty) * W_hh[ty*128+col][i*32+tt*8..+7]
  half8 w[4][4];                    // 64 VGPRs, shared by both batches
  #pragma unroll
  for (int ty = 0; ty < 4; ++ty) {
    const float sc = (ty == 2) ? (-2.0f * LOG2E) : (-LOG2E);
    const float* wrow = Whh + (size_t)(ty * 128 + col) * H_SZ + tt * 8;
    #pragma unroll
    for (int i = 0; i < 4; ++i) {
      floatx4 v0 = *(const floatx4*)(wrow + i * 32);
      floatx4 v1 = *(const floatx4*)(wrow + i * 32 + 4);
      half8 hh;
      hh[0] = (_Float16)(v0.x * sc); hh[1] = (_Float16)(v0.y * sc);
      hh[2] = (_Float16)(v0.z * sc); hh[3] = (_Float16)(v0.w * sc);
      hh[4] = (_Float16)(v1.x * sc); hh[5] = (_Float16)(v1.y * sc);
      hh[6] = (_Float16)(v1.z * sc); hh[7] = (_Float16)(v1.w * sc);
      w[ty][i] = hh;
    }
  }

  const float wt = -LOG2E * w_tp[col];
  const float bt = -LOG2E * b_tp[col];
  const float am  = (tt == 2) ? 2.0f : 1.0f;
  const float aa  = (tt == 2) ? -1.0f : 0.0f;
  const bool  odd = (tt & 1) != 0;

  ((_Float16*)hbuf)[tid] = (_Float16)0.0f;   // 512 entries == 512 threads
  __syncthreads();

  // gx element index for row t: (t<<15) + go{0,1}   (B*G4 = 32768 = 1<<15)
  const size_t go0 = (size_t)b0 * G4 + j;
  const size_t go1 = go0 + G4;

  // distance-2 prefetch pipeline: r0* = row t (ready), r1* = row t-1 (in flight)
  _Float16 r0a = gx[((size_t)(S_LEN - 1) << 15) + go0];
  _Float16 r0b = gx[((size_t)(S_LEN - 1) << 15) + go1];
  _Float16 r1a = gx[((size_t)(S_LEN - 2) << 15) + go0];
  _Float16 r1b = gx[((size_t)(S_LEN - 2) << 15) + go1];
  floatx2 tm0 = *(const floatx2*)(timep + ((S_LEN - 1) << 6) + b0);
  floatx2 tm1 = *(const floatx2*)(timep + ((S_LEN - 2) << 6) + b0);

  float c0 = 0.0f, c1 = 0.0f;

  for (int t = S_LEN - 1; t > 0; t -= 2) {
    // ---- substep A: T = t, read pingpong 0, write pingpong 1 ----
    {
      const int tl = (t >= 2) ? (t - 2) : 0;
      _Float16 r2a = gx[((size_t)tl << 15) + go0];
      _Float16 r2b = gx[((size_t)tl << 15) + go1];
      floatx2 tm2 = *(const floatx2*)(timep + (tl << 6) + b0);
      const float g0 = (float)r0a;
      const float g1 = (float)r0b;
      float h0 = lstm_gate(&hbuf[0][0][0], w, g0, tm0.x, c0,
                           wt, bt, am, aa, odd, tt);
      float h1 = lstm_gate(&hbuf[1][0][0], w, g1, tm0.y, c1,
                           wt, bt, am, aa, odd, tt);
      if (tt == 3) {
        hbuf[0][1][col] = (_Float16)h0;
        hbuf[1][1][col] = (_Float16)h1;
        float* o = out + ((size_t)t << 13) + (size_t)b0 * H_SZ + col;
        o[0]    = h0;
        o[H_SZ] = h1;
      }
      lds_barrier();
      r0a = r1a; r0b = r1b; r1a = r2a; r1b = r2b;
      tm0 = tm1; tm1 = tm2;
    }
    // ---- substep B: T = t-1, read pingpong 1, write pingpong 0 ----
    {
      const int T  = t - 1;
      const int tl = (T >= 2) ? (T - 2) : 0;
      _Float16 r2a = gx[((size_t)tl << 15) + go0];
      _Float16 r2b = gx[((size_t)tl << 15) + go1];
      floatx2 tm2 = *(const floatx2*)(timep + (tl << 6) + b0);
      const float g0 = (float)r0a;
      const float g1 = (float)r0b;
      float h0 = lstm_gate(&hbuf[0][1][0], w, g0, tm0.x, c0,
                           wt, bt, am, aa, odd, tt);
      float h1 = lstm_gate(&hbuf[1][1][0], w, g1, tm0.y, c1,
                           wt, bt, am, aa, odd, tt);
      if (tt == 3) {
        hbuf[0][0][col] = (_Float16)h0;
        hbuf[1][0][col] = (_Float16)h1;
        float* o = out + ((size_t)T << 13) + (size_t)b0 * H_SZ + col;
        o[0]    = h0;
        o[H_SZ] = h1;
        if (T == 0) {
          float* hf = out + (size_t)S_LEN * B_SZ * H_SZ;
          hf[(size_t)b0 * H_SZ + col]       = h0;
          hf[(size_t)(b0 + 1) * H_SZ + col] = h1;
          float* cf = hf + (size_t)B_SZ * H_SZ;
          cf[(size_t)b0 * H_SZ + col]       = c0;
          cf[(size_t)(b0 + 1) * H_SZ + col] = c1;
        }
      }
      lds_barrier();
      r0a = r1a; r0b = r1b; r1a = r2a; r1b = r2b;
      tm0 = tm1; tm1 = tm2;
    }
  }
}

// ---------------------------------------------------------------------------
extern "C" void kernel_launch(void* const* d_in, const int* in_sizes, int n_in,
                              void* d_out, int out_size, void* d_ws, size_t ws_size,
                              hipStream_t stream) {
  const float* input = (const float*)d_in[0];   // (S,B,D)
  const float* timep = (const float*)d_in[1];   // (S,B,1)
  const float* W_ih  = (const float*)d_in[2];   // (4H,D)
  const float* W_hh  = (const float*)d_in[3];   // (4H,H)
  const float* bias  = (const float*)d_in[4];   // (4H,)
  const float* w_t   = (const float*)d_in[5];   // (H,)
  const float* b_t   = (const float*)d_in[6];   // (H,)
  float* out = (float*)d_out;

  _Float16* gx = (_Float16*)d_ws;   // 2048*64*512*2 = 128 MiB

  gx_gemm<<<dim3((S_LEN * B_SZ) / 256), dim3(256), 0, stream>>>(
      input, W_ih, bias, gx);

  lstm_rev<<<dim3(B_SZ / 2), dim3(512), 0, stream>>>(
      gx, timep, W_hh, w_t, b_t, out);
}